// Round 2
// baseline (461.586 us; speedup 1.0000x reference)
//
#include <hip/hip_runtime.h>

#define BATCH 524288
#define NOISE_STD 0.4466835921509630f
#define INV_SQRT2 0.7071067811865476f

__device__ __forceinline__ float eluf(float x) {
    return x > 0.0f ? x : __expf(x) - 1.0f;
}

__device__ __forceinline__ float ftanh(float x) {
    float xc = fminf(fmaxf(x, -12.0f), 12.0f);
    float t = __expf(2.0f * xc);
    return 1.0f - __fdividef(2.0f, t + 1.0f);
}

__global__ __launch_bounds__(256) void enc_kernel(
    const float* __restrict__ x,
    const float* __restrict__ w1, const float* __restrict__ b1,
    const float* __restrict__ w2, const float* __restrict__ b2,
    const float* __restrict__ cw1, const float* __restrict__ cb1,
    const float* __restrict__ cw2, const float* __restrict__ cb2,
    const float* __restrict__ cw3, const float* __restrict__ cb3,
    const float* __restrict__ cw4, const float* __restrict__ cb4,
    const float* __restrict__ w3, const float* __restrict__ b3,
    const float* __restrict__ w4, const float* __restrict__ b4,
    float* __restrict__ g_out, float* __restrict__ partials)
{
    const int row = blockIdx.x * 256 + threadIdx.x;

    float v[16];
    {
        const float4* xp = (const float4*)(x + (size_t)row * 16);
        float4 a0 = xp[0], a1 = xp[1], a2 = xp[2], a3 = xp[3];
        v[0]=a0.x; v[1]=a0.y; v[2]=a0.z; v[3]=a0.w;
        v[4]=a1.x; v[5]=a1.y; v[6]=a1.z; v[7]=a1.w;
        v[8]=a2.x; v[9]=a2.y; v[10]=a2.z; v[11]=a2.w;
        v[12]=a3.x; v[13]=a3.y; v[14]=a3.z; v[15]=a3.w;
    }

    // dense1: (16) @ (16,16) + b1, ELU
    float h1[16];
#pragma unroll
    for (int j = 0; j < 16; ++j) h1[j] = b1[j];
#pragma unroll
    for (int i = 0; i < 16; ++i) {
        float vi = v[i];
#pragma unroll
        for (int j = 0; j < 16; ++j) h1[j] += vi * w1[i*16+j];
    }
#pragma unroll
    for (int j = 0; j < 16; ++j) h1[j] = eluf(h1[j]);

    // dense2: (16) @ (16,16) + b2, ELU
    float h2[16];
#pragma unroll
    for (int j = 0; j < 16; ++j) h2[j] = b2[j];
#pragma unroll
    for (int i = 0; i < 16; ++i) {
        float vi = h1[i];
#pragma unroll
        for (int j = 0; j < 16; ++j) h2[j] += vi * w2[i*16+j];
    }
#pragma unroll
    for (int j = 0; j < 16; ++j) h2[j] = eluf(h2[j]);

    // conv1 (1ch->8ch, k=2, s=1) fused with conv2 (8->8, k=4, s=2) via rolling window.
    // conv2 uses conv1 positions 0..13 only (position 14 is dead in the reference).
    float win[8][4];   // conv1 outputs at positions 2p .. 2p+3
#pragma unroll
    for (int k = 0; k < 4; ++k)
#pragma unroll
        for (int ic = 0; ic < 8; ++ic)
            win[ic][k] = ftanh(cb1[ic] + cw1[ic*2]*h2[k] + cw1[ic*2+1]*h2[k+1]);

    float o2[8][6];
#pragma unroll
    for (int p = 0; p < 6; ++p) {
#pragma unroll
        for (int oc = 0; oc < 8; ++oc) {
            float acc = cb2[oc];
#pragma unroll
            for (int ic = 0; ic < 8; ++ic)
#pragma unroll
                for (int k = 0; k < 4; ++k)
                    acc += cw2[oc*32+ic*4+k] * win[ic][k];
            o2[oc][p] = ftanh(acc);
        }
        if (p < 5) {
#pragma unroll
            for (int ic = 0; ic < 8; ++ic) {
                win[ic][0] = win[ic][2];
                win[ic][1] = win[ic][3];
                win[ic][2] = ftanh(cb1[ic] + cw1[ic*2]*h2[2*p+4] + cw1[ic*2+1]*h2[2*p+5]);
                win[ic][3] = ftanh(cb1[ic] + cw1[ic*2]*h2[2*p+5] + cw1[ic*2+1]*h2[2*p+6]);
            }
        }
    }

    // conv3 (8->8, k=2, s=1): 6 -> 5
    float o3[8][5];
#pragma unroll
    for (int p = 0; p < 5; ++p)
#pragma unroll
        for (int oc = 0; oc < 8; ++oc) {
            float acc = cb3[oc];
#pragma unroll
            for (int ic = 0; ic < 8; ++ic)
                acc += cw3[oc*16+ic*2]*o2[ic][p] + cw3[oc*16+ic*2+1]*o2[ic][p+1];
            o3[oc][p] = ftanh(acc);
        }

    // conv4 (8->8, k=2, s=1): 5 -> 4
    float o4[8][4];
#pragma unroll
    for (int p = 0; p < 4; ++p)
#pragma unroll
        for (int oc = 0; oc < 8; ++oc) {
            float acc = cb4[oc];
#pragma unroll
            for (int ic = 0; ic < 8; ++ic)
                acc += cw4[oc*16+ic*2]*o3[ic][p] + cw4[oc*16+ic*2+1]*o3[ic][p+1];
            o4[oc][p] = ftanh(acc);
        }

    // flatten (ch-major) -> dense w3 (32,32), tanh
    float t3[32];
#pragma unroll
    for (int j = 0; j < 32; ++j) t3[j] = b3[j];
#pragma unroll
    for (int oc = 0; oc < 8; ++oc)
#pragma unroll
        for (int p = 0; p < 4; ++p) {
            float fv = o4[oc][p];
            const int i = oc*4 + p;
#pragma unroll
            for (int j = 0; j < 32; ++j) t3[j] += fv * w3[i*32+j];
        }
#pragma unroll
    for (int j = 0; j < 32; ++j) t3[j] = ftanh(t3[j]);

    // dense w4 (32,16) -> pre-norm code g
    float g[16];
#pragma unroll
    for (int j = 0; j < 16; ++j) g[j] = b4[j];
#pragma unroll
    for (int i = 0; i < 32; ++i) {
        float fv = t3[i];
#pragma unroll
        for (int j = 0; j < 16; ++j) g[j] += fv * w4[i*16+j];
    }

    {
        float4* gp = (float4*)(g_out + (size_t)row * 16);
        gp[0] = make_float4(g[0],g[1],g[2],g[3]);
        gp[1] = make_float4(g[4],g[5],g[6],g[7]);
        gp[2] = make_float4(g[8],g[9],g[10],g[11]);
        gp[3] = make_float4(g[12],g[13],g[14],g[15]);
    }

    // per-block column sums and sumsq (deterministic, no atomics)
    __shared__ float red[4][32];
    const int lane = threadIdx.x & 63;
    const int wid = threadIdx.x >> 6;
#pragma unroll
    for (int c = 0; c < 16; ++c) {
        float s = g[c];
        float q = g[c]*g[c];
#pragma unroll
        for (int off = 32; off > 0; off >>= 1) {
            s += __shfl_xor(s, off);
            q += __shfl_xor(q, off);
        }
        if (lane == c)      red[wid][c]      = s;
        if (lane == 16 + c) red[wid][16 + c] = q;
    }
    __syncthreads();
    if (threadIdx.x < 32) {
        float t = red[0][threadIdx.x] + red[1][threadIdx.x]
                + red[2][threadIdx.x] + red[3][threadIdx.x];
        partials[blockIdx.x * 32 + threadIdx.x] = t;
    }
}

__global__ void stat_kernel(const float* __restrict__ partials,
                            float* __restrict__ muinv, int nblocks)
{
    __shared__ float lds[256];
    const int t = threadIdx.x;
    const int c = t & 31, chunk = t >> 5;   // 8 chunks x 32 cols
    float s = 0.0f;
    for (int b = chunk; b < nblocks; b += 8) s += partials[b*32 + c];
    lds[t] = s;
    __syncthreads();
    if (t < 32) {
        float tot = 0.0f;
#pragma unroll
        for (int k = 0; k < 8; ++k) tot += lds[k*32 + t];
        lds[t] = tot;
    }
    __syncthreads();
    if (t < 16) {
        float mu  = lds[t] * (1.0f / (float)BATCH);
        float var = lds[16 + t] * (1.0f / (float)BATCH) - mu * mu;
        muinv[t]      = mu;
        muinv[16 + t] = rsqrtf(var + 1e-5f);
    }
}

__global__ __launch_bounds__(256) void dec_kernel(
    const float* __restrict__ g_in,
    const float* __restrict__ noise,
    const float* __restrict__ fading,
    const float* __restrict__ muinv,
    const float* __restrict__ dw1, const float* __restrict__ db1,
    const float* __restrict__ dw2, const float* __restrict__ db2,
    float* __restrict__ out)
{
    const int row = blockIdx.x * 256 + threadIdx.x;

    float enc[16];
    {
        const float4* gp = (const float4*)(g_in + (size_t)row * 16);
        float4 a0 = gp[0], a1 = gp[1], a2 = gp[2], a3 = gp[3];
        float g[16] = {a0.x,a0.y,a0.z,a0.w, a1.x,a1.y,a1.z,a1.w,
                       a2.x,a2.y,a2.z,a2.w, a3.x,a3.y,a3.z,a3.w};
#pragma unroll
        for (int c = 0; c < 16; ++c)
            enc[c] = (g[c] - muinv[c]) * muinv[16 + c];
    }

    float hr[3], hi[3];
    {
        const float2* fd = (const float2*)(fading + (size_t)row * 6);
        float2 f0 = fd[0], f1 = fd[1], f2 = fd[2];
        hr[0] = f0.x * INV_SQRT2; hi[0] = f0.y * INV_SQRT2;
        hr[1] = f1.x * INV_SQRT2; hi[1] = f1.y * INV_SQRT2;
        hr[2] = f2.x * INV_SQRT2; hi[2] = f2.y * INV_SQRT2;
    }

    // causal 3-tap complex conv: out[n] = sum_t hc[t] * xc[n-t], xc[<0]=0
    float cvec[16];
    {
        const float4* npz = (const float4*)(noise + (size_t)row * 16);
        float4 n0 = npz[0], n1 = npz[1], n2 = npz[2], n3 = npz[3];
        float nz[16] = {n0.x,n0.y,n0.z,n0.w, n1.x,n1.y,n1.z,n1.w,
                        n2.x,n2.y,n2.z,n2.w, n3.x,n3.y,n3.z,n3.w};
#pragma unroll
        for (int n = 0; n < 8; ++n) {
            float sr = 0.0f, si = 0.0f;
#pragma unroll
            for (int t = 0; t < 3; ++t) {
                if (n - t >= 0) {
                    float xr = enc[2*(n-t)], xi = enc[2*(n-t)+1];
                    sr += hr[t]*xr - hi[t]*xi;
                    si += hr[t]*xi + hi[t]*xr;
                }
            }
            cvec[2*n]   = sr + nz[2*n]   * NOISE_STD;
            cvec[2*n+1] = si + nz[2*n+1] * NOISE_STD;
        }
    }

    // decoder dense1: (16) @ (16,32) + db1, ELU
    float d[32];
#pragma unroll
    for (int j = 0; j < 32; ++j) d[j] = db1[j];
#pragma unroll
    for (int i = 0; i < 16; ++i) {
        float ci = cvec[i];
#pragma unroll
        for (int j = 0; j < 32; ++j) d[j] += ci * dw1[i*32+j];
    }
#pragma unroll
    for (int j = 0; j < 32; ++j) d[j] = eluf(d[j]);

    // decoder dense2: (32) @ (32,16) + db2
    float o[16];
#pragma unroll
    for (int j = 0; j < 16; ++j) o[j] = db2[j];
#pragma unroll
    for (int i = 0; i < 32; ++i) {
        float di = d[i];
#pragma unroll
        for (int j = 0; j < 16; ++j) o[j] += di * dw2[i*16+j];
    }

    float4* op = (float4*)(out + (size_t)row * 16);
    op[0] = make_float4(o[0],o[1],o[2],o[3]);
    op[1] = make_float4(o[4],o[5],o[6],o[7]);
    op[2] = make_float4(o[8],o[9],o[10],o[11]);
    op[3] = make_float4(o[12],o[13],o[14],o[15]);
}

extern "C" void kernel_launch(void* const* d_in, const int* in_sizes, int n_in,
                              void* d_out, int out_size, void* d_ws, size_t ws_size,
                              hipStream_t stream) {
    (void)in_sizes; (void)n_in; (void)out_size; (void)ws_size;

    const float* x      = (const float*)d_in[0];
    const float* noise  = (const float*)d_in[1];
    const float* fading = (const float*)d_in[2];
    const float* w1  = (const float*)d_in[3];
    const float* b1  = (const float*)d_in[4];
    const float* w2  = (const float*)d_in[5];
    const float* b2  = (const float*)d_in[6];
    const float* cw1 = (const float*)d_in[7];
    const float* cb1 = (const float*)d_in[8];
    const float* cw2 = (const float*)d_in[9];
    const float* cb2 = (const float*)d_in[10];
    const float* cw3 = (const float*)d_in[11];
    const float* cb3 = (const float*)d_in[12];
    const float* cw4 = (const float*)d_in[13];
    const float* cb4 = (const float*)d_in[14];
    const float* w3  = (const float*)d_in[15];
    const float* b3  = (const float*)d_in[16];
    const float* w4  = (const float*)d_in[17];
    const float* b4  = (const float*)d_in[18];
    const float* dw1 = (const float*)d_in[19];
    const float* db1 = (const float*)d_in[20];
    const float* dw2 = (const float*)d_in[21];
    const float* db2 = (const float*)d_in[22];
    float* outp = (float*)d_out;

    float* ws       = (float*)d_ws;
    float* muinv    = ws;                 // 32 floats
    float* partials = ws + 32;            // 2048*32 floats
    float* g        = ws + 32 + 2048*32;  // BATCH*16 floats

    const int nb = BATCH / 256;  // 2048

    enc_kernel<<<nb, 256, 0, stream>>>(x, w1,b1, w2,b2, cw1,cb1, cw2,cb2,
                                       cw3,cb3, cw4,cb4, w3,b3, w4,b4,
                                       g, partials);
    stat_kernel<<<1, 256, 0, stream>>>(partials, muinv, nb);
    dec_kernel<<<nb, 256, 0, stream>>>(g, noise, fading, muinv,
                                       dw1,db1, dw2,db2, outp);
}